// Round 3
// baseline (275.151 us; speedup 1.0000x reference)
//
#include <hip/hip_runtime.h>

#define IMG    512
#define TW     32
#define TH     48
#define R      5
#define KW     11
#define HB_H   (TH + 2*R)            // 58
#define W4     33                    // hb4 padded width (float4 cells)
#define W1     36                    // hb1 padded width (floats), keeps 16B align
#define GX     (IMG / TW)            // 16
#define GY     ((IMG + TH - 1) / TH) // 11 (last tile: rows 480..527, 32 valid)
#define NBATCH 32
#define NBLOCKS (GX * GY * NBATCH)   // 5632
#define C1f 0.0001f
#define C2f 0.0009f

__global__ __launch_bounds__(256, 4) void ssim_fused_kernel(
    const float* __restrict__ x, const float* __restrict__ y,
    float* __restrict__ out, float* __restrict__ ws)
{
    __shared__ float4 hb4[HB_H][W4];  // (mu_x, mu_y, E[xx], E[yy]) after horiz pass
    __shared__ float  hb1[HB_H][W1];  // E[xy] after horiz pass
    __shared__ float  red[4];

    // normalized 1D Gaussian, sigma=1.5, k=11 (precomputed; ~1e-7 vs expf)
    const float W[KW] = {
        0.00102838f, 0.00759874f, 0.03600077f, 0.10936075f, 0.21300553f,
        0.26601172f,
        0.21300553f, 0.10936075f, 0.03600077f, 0.00759874f, 0.00102838f};

    const int tc = blockIdx.x, tr = blockIdx.y, b = blockIdx.z;
    const int tid = threadIdx.x;
    const size_t imgBase = (size_t)b * (IMG * IMG);
    const int gr0 = tr * TH - R;
    const bool colEdge = (tc == 0) || (tc == GX - 1);

    // ================= horizontal pass: one 8-px group per thread =================
    if (tid < HB_H * 4) {
        const int rr = tid >> 2;     // staged row 0..57
        const int g  = tid & 3;      // 8-px group in row
        const int gr = gr0 + rr;
        float4* h4 = &hb4[rr][8 * g];
        float*  h1 = &hb1[rr][8 * g];
        if ((unsigned)gr < (unsigned)IMG) {
            const float4* rx = (const float4*)(x + imgBase + (size_t)gr * IMG);
            const float4* ry = (const float4*)(y + imgBase + (size_t)gr * IMG);
            const int q0 = tc * 8 + 2 * g - 2;   // first float4 index
            float fx[24], fy[24];
            if (colEdge) {
#pragma unroll
                for (int i = 0; i < 6; ++i) {
                    int q = q0 + i;
                    int qc = min(max(q, 0), IMG / 4 - 1);
                    float4 vx = rx[qc], vy = ry[qc];
                    float m = (q == qc) ? 1.f : 0.f;
                    fx[4*i+0]=vx.x*m; fx[4*i+1]=vx.y*m; fx[4*i+2]=vx.z*m; fx[4*i+3]=vx.w*m;
                    fy[4*i+0]=vy.x*m; fy[4*i+1]=vy.y*m; fy[4*i+2]=vy.z*m; fy[4*i+3]=vy.w*m;
                }
            } else {
#pragma unroll
                for (int i = 0; i < 6; ++i) {
                    float4 vx = rx[q0 + i], vy = ry[q0 + i];
                    fx[4*i+0]=vx.x; fx[4*i+1]=vx.y; fx[4*i+2]=vx.z; fx[4*i+3]=vx.w;
                    fy[4*i+0]=vy.x; fy[4*i+1]=vy.y; fy[4*i+2]=vy.z; fy[4*i+3]=vy.w;
                }
            }
            // ---- half A: output cols 8g+0..3, inputs f[3..16]
            {
                float a0[4]={0,0,0,0}, a1[4]={0,0,0,0}, a2[4]={0,0,0,0},
                      a3[4]={0,0,0,0}, a4[4]={0,0,0,0};
#pragma unroll
                for (int j = 3; j <= 16; ++j) {
                    float px = fx[j], py = fy[j];
                    float xx = px*px, yy = py*py, xy = px*py;
#pragma unroll
                    for (int k = 0; k < 4; ++k) {
                        const int t = j - 3 - k;
                        if (t >= 0 && t < KW) {
                            const float wt = W[t];
                            a0[k] += wt*px; a1[k] += wt*py;
                            a2[k] += wt*xx; a3[k] += wt*yy; a4[k] += wt*xy;
                        }
                    }
                }
#pragma unroll
                for (int k = 0; k < 4; ++k)
                    h4[k] = make_float4(a0[k], a1[k], a2[k], a3[k]);
                *(float4*)h1 = make_float4(a4[0], a4[1], a4[2], a4[3]);
            }
            // ---- half B: output cols 8g+4..7, inputs f[7..20]
            {
                float a0[4]={0,0,0,0}, a1[4]={0,0,0,0}, a2[4]={0,0,0,0},
                      a3[4]={0,0,0,0}, a4[4]={0,0,0,0};
#pragma unroll
                for (int j = 7; j <= 20; ++j) {
                    float px = fx[j], py = fy[j];
                    float xx = px*px, yy = py*py, xy = px*py;
#pragma unroll
                    for (int k = 0; k < 4; ++k) {
                        const int t = j - 7 - k;   // tap for output 4+k
                        if (t >= 0 && t < KW) {
                            const float wt = W[t];
                            a0[k] += wt*px; a1[k] += wt*py;
                            a2[k] += wt*xx; a3[k] += wt*yy; a4[k] += wt*xy;
                        }
                    }
                }
#pragma unroll
                for (int k = 0; k < 4; ++k)
                    h4[4 + k] = make_float4(a0[k], a1[k], a2[k], a3[k]);
                *(float4*)(h1 + 4) = make_float4(a4[0], a4[1], a4[2], a4[3]);
            }
        } else {
            // out-of-image row: contributes zeros
            const float4 z = make_float4(0.f, 0.f, 0.f, 0.f);
#pragma unroll
            for (int k = 0; k < 8; ++k) h4[k] = z;
            *(float4*)h1 = z;
            *(float4*)(h1 + 4) = z;
        }
    }
    __syncthreads();

    // ================= vertical pass + SSIM epilogue =================
    const int tx = tid & 31;        // column in tile
    const int ty = tid >> 5;        // 0..7 -> rows [6*ty, 6*ty+6)
    const int r0 = ty * 6;

    float a0[6], a1[6], a2[6], a3[6], a4[6];
#pragma unroll
    for (int k = 0; k < 6; ++k) { a0[k]=0.f; a1[k]=0.f; a2[k]=0.f; a3[k]=0.f; a4[k]=0.f; }

#pragma unroll
    for (int t = 0; t < 16; ++t) {
        float4 v4 = hb4[r0 + t][tx];
        float  v1 = hb1[r0 + t][tx];
#pragma unroll
        for (int k = 0; k < 6; ++k) {
            const int u = t - k;
            if (u >= 0 && u < KW) {     // constant-folds under full unroll
                const float wt = W[u];
                a0[k] += wt * v4.x;
                a1[k] += wt * v4.y;
                a2[k] += wt * v4.z;
                a3[k] += wt * v4.w;
                a4[k] += wt * v1;
            }
        }
    }

    float lsum = 0.f;
    const int grOut = tr * TH + r0;
#pragma unroll
    for (int k = 0; k < 6; ++k) {
        float mux = a0[k], muy = a1[k];
        float sxx = a2[k] - mux * mux;
        float syy = a3[k] - muy * muy;
        float sxy = a4[k] - mux * muy;
        float num = (2.f * mux * muy + C1f) * (2.f * sxy + C2f);
        float den = (mux * mux + muy * muy + C1f) * (sxx + syy + C2f);
        float ssim = num / (den + 1e-12f);
        ssim = fminf(fmaxf(ssim, -1.f + 1e-6f), 1.f - 1e-6f);
        lsum += (grOut + k < IMG) ? ssim : 0.f;
    }

    // ================= block reduction + fused finalize =================
#pragma unroll
    for (int off = 32; off > 0; off >>= 1)
        lsum += __shfl_down(lsum, off, 64);
    if ((tid & 63) == 0) red[tid >> 6] = lsum;
    __syncthreads();
    if (tid == 0) {
        float s = red[0] + red[1] + red[2] + red[3];
        atomicAdd(&ws[0], s);                       // device-scope by default
        __threadfence();
        unsigned old = atomicAdd((unsigned*)&ws[1], 1u);
        if (old == (unsigned)(NBLOCKS - 1)) {       // last block finalizes
            __threadfence();
            float tot = atomicAdd(&ws[0], 0.0f);    // coherent read
            out[0] = 1.0f - tot * (1.0f / (32.0f * 512.0f * 512.0f));
        }
    }
}

extern "C" void kernel_launch(void* const* d_in, const int* in_sizes, int n_in,
                              void* d_out, int out_size, void* d_ws, size_t ws_size,
                              hipStream_t stream) {
    const float* x = (const float*)d_in[0];
    const float* y = (const float*)d_in[1];
    float* out = (float*)d_out;
    float* ws  = (float*)d_ws;   // ws[0]=sum accumulator, ws[1]=done counter

    hipMemsetAsync(d_ws, 0, 2 * sizeof(float), stream);  // graph-capture legal
    dim3 grid(GX, GY, NBATCH);
    ssim_fused_kernel<<<grid, 256, 0, stream>>>(x, y, out, ws);
}